// Round 1
// baseline (672.354 us; speedup 1.0000x reference)
//
#include <hip/hip_runtime.h>
#include <hip/hip_bf16.h>
#include <math.h>

#define B_    2
#define L_    1024
#define H_    12
#define D_    64
#define HID_  768
#define TOPK_ 32
#define NEG_  (-100000000.0f)

// ---------------------------------------------------------------------------
// bias vector for the fused qkv GEMM: [q_bias | zeros | v_bias]
// ---------------------------------------------------------------------------
__global__ void prep_bias(const float* __restrict__ qb_,
                          const float* __restrict__ vb_,
                          float* __restrict__ biasq) {
    int n = blockIdx.x * 256 + threadIdx.x;
    if (n >= 3 * HID_) return;
    float v = 0.f;
    if (n < HID_) v = qb_[n];
    else if (n >= 2 * HID_) v = vb_[n - 2 * HID_];
    biasq[n] = v;
}

// ---------------------------------------------------------------------------
// fp32 GEMM: C[M,N] = A[M,K] @ B[K,N] + bias[N]; 128x128x16 tile, 256 thr,
// 8x8 per-thread microtile. M,N,K must be multiples of 128/128/16 (they are).
// ---------------------------------------------------------------------------
__global__ __launch_bounds__(256) void gemm_f32(
    const float* __restrict__ A, int lda,
    const float* __restrict__ Bm, int ldb,
    const float* __restrict__ bias,
    float* __restrict__ C, int ldc,
    int M, int N, int K)
{
    __shared__ __align__(16) float As[16][132];   // transposed A tile (+pad)
    __shared__ __align__(16) float Bs[16][128];

    const int tid = threadIdx.x;
    const int tx = tid & 15, ty = tid >> 4;
    const int bn = blockIdx.x * 128;
    const int bm = blockIdx.y * 128;

    const int arow = tid >> 1;            // 0..127
    const int akq  = (tid & 1) * 8;       // 0 or 8
    const int bkr  = tid >> 4;            // 0..15
    const int bnq  = (tid & 15) * 8;      // 0..120

    const float* Aptr = A + (size_t)(bm + arow) * lda + akq;
    const float* Bptr = Bm + (size_t)bkr * ldb + bn + bnq;

    float acc[8][8];
#pragma unroll
    for (int r = 0; r < 8; ++r)
#pragma unroll
        for (int c = 0; c < 8; ++c) acc[r][c] = 0.f;

    float4 a0 = *(const float4*)(Aptr);
    float4 a1 = *(const float4*)(Aptr + 4);
    float4 b0 = *(const float4*)(Bptr);
    float4 b1 = *(const float4*)(Bptr + 4);

    for (int k0 = 0; k0 < K; k0 += 16) {
        __syncthreads();
        As[akq + 0][arow] = a0.x; As[akq + 1][arow] = a0.y;
        As[akq + 2][arow] = a0.z; As[akq + 3][arow] = a0.w;
        As[akq + 4][arow] = a1.x; As[akq + 5][arow] = a1.y;
        As[akq + 6][arow] = a1.z; As[akq + 7][arow] = a1.w;
        *(float4*)(&Bs[bkr][bnq])     = b0;
        *(float4*)(&Bs[bkr][bnq + 4]) = b1;
        __syncthreads();

        if (k0 + 16 < K) {  // prefetch next tile while computing this one
            a0 = *(const float4*)(Aptr + k0 + 16);
            a1 = *(const float4*)(Aptr + k0 + 20);
            b0 = *(const float4*)(Bptr + (size_t)(k0 + 16) * ldb);
            b1 = *(const float4*)(Bptr + (size_t)(k0 + 16) * ldb + 4);
        }

#pragma unroll
        for (int kk = 0; kk < 16; ++kk) {
            const float4 av0 = *(const float4*)(&As[kk][ty * 8]);
            const float4 av1 = *(const float4*)(&As[kk][ty * 8 + 4]);
            const float4 bv0 = *(const float4*)(&Bs[kk][tx * 8]);
            const float4 bv1 = *(const float4*)(&Bs[kk][tx * 8 + 4]);
            const float a_[8] = {av0.x, av0.y, av0.z, av0.w, av1.x, av1.y, av1.z, av1.w};
            const float b_[8] = {bv0.x, bv0.y, bv0.z, bv0.w, bv1.x, bv1.y, bv1.z, bv1.w};
#pragma unroll
            for (int r = 0; r < 8; ++r)
#pragma unroll
                for (int c = 0; c < 8; ++c)
                    acc[r][c] = fmaf(a_[r], b_[c], acc[r][c]);
        }
    }

    float bv[8];
#pragma unroll
    for (int c = 0; c < 8; ++c) bv[c] = bias ? bias[bn + tx * 8 + c] : 0.f;

#pragma unroll
    for (int r = 0; r < 8; ++r) {
        float* crow = C + (size_t)(bm + ty * 8 + r) * ldc + bn + tx * 8;
        float4 o0, o1;
        o0.x = acc[r][0] + bv[0]; o0.y = acc[r][1] + bv[1];
        o0.z = acc[r][2] + bv[2]; o0.w = acc[r][3] + bv[3];
        o1.x = acc[r][4] + bv[4]; o1.y = acc[r][5] + bv[5];
        o1.z = acc[r][6] + bv[6]; o1.w = acc[r][7] + bv[7];
        *(float4*)crow       = o0;
        *(float4*)(crow + 4) = o1;
    }
}

// ---------------------------------------------------------------------------
// Sparse gather-attention. One block per (b,i); 384 threads (6 waves).
// All 12 heads share the TOPK=32 index set.
// ---------------------------------------------------------------------------
__global__ __launch_bounds__(384) void attn_kernel(
    const float* __restrict__ qkv,   // [B*L][2304]  q|k|v (biases applied)
    const float* __restrict__ qb,    // [B*L][768]   q@w_rq + b_rq
    const float* __restrict__ rbe,   // [B*L][32][768]
    const int*   __restrict__ ridx,  // [B*L][32]
    const unsigned char* __restrict__ amask, // [B][L][L] bool
    const float* __restrict__ rel_pos,   // [B][12][L][L]
    const float* __restrict__ rel2d,     // [B][12][L][L]
    float* __restrict__ out)             // [B*L][768]
{
    const int bi = blockIdx.x;          // b*L + i
    const int b = bi >> 10, i = bi & (L_ - 1);
    const int tid = threadIdx.x;
    const float scale = 0.125f;         // 1/sqrt(64)

    __shared__ __align__(16) float sQ[HID_];
    __shared__ __align__(16) float sQb[HID_];
    __shared__ int   sIdx[TOPK_];
    __shared__ unsigned char sFirst[TOPK_];
    __shared__ float sBbox[H_][TOPK_ + 1];
    __shared__ float sScore[H_][TOPK_ + 1];
    __shared__ float sProb[H_][TOPK_ + 1];

    // load q, qb rows (scale folded in); load index set
    {
        const float* qrow  = qkv + (size_t)bi * (3 * HID_);
        const float* qbrow = qb + (size_t)bi * HID_;
        for (int d = tid; d < HID_; d += 384) {
            sQ[d]  = qrow[d]  * scale;
            sQb[d] = qbrow[d] * scale;
        }
        if (tid < TOPK_) sIdx[tid] = ridx[bi * TOPK_ + tid];
    }
    __syncthreads();

    if (tid < TOPK_) {  // first-occurrence flags for duplicate indices
        int j = sIdx[tid];
        unsigned char f = 1;
        for (int t2 = 0; t2 < tid; ++t2)
            if (sIdx[t2] == j) { f = 0; break; }
        sFirst[tid] = f;
    }

    const int grp = tid >> 4;   // 0..23 (16-lane groups)
    const int l16 = tid & 15;

    // --- bbox scores: sBbox[h][t] = scale * qb_h . rbe[b,i,t,h,:] ---
#pragma unroll 4
    for (int it = 0; it < 16; ++it) {
        int p = it * 24 + grp;              // 0..383 pair id
        int t = p / 12, h = p - t * 12;
        const float4 r4 = *(const float4*)(rbe + (((size_t)bi * TOPK_ + t) * HID_) + h * D_ + l16 * 4);
        const float4 q4 = *(const float4*)(sQb + h * D_ + l16 * 4);
        float s = r4.x * q4.x + r4.y * q4.y + r4.z * q4.z + r4.w * q4.w;
        s += __shfl_xor(s, 1); s += __shfl_xor(s, 2);
        s += __shfl_xor(s, 4); s += __shfl_xor(s, 8);
        if (l16 == 0) sBbox[h][t] = s;
    }

    // --- qk scores + rel gathers: sScore[h][t] ---
#pragma unroll 4
    for (int it = 0; it < 16; ++it) {
        int p = it * 24 + grp;
        int t = p / 12, h = p - t * 12;
        int j = sIdx[t];
        const float4 k4 = *(const float4*)(qkv + (size_t)(b * L_ + j) * (3 * HID_) + HID_ + h * D_ + l16 * 4);
        const float4 q4 = *(const float4*)(sQ + h * D_ + l16 * 4);
        float s = k4.x * q4.x + k4.y * q4.y + k4.z * q4.z + k4.w * q4.w;
        s += __shfl_xor(s, 1); s += __shfl_xor(s, 2);
        s += __shfl_xor(s, 4); s += __shfl_xor(s, 8);
        if (l16 == 0) {
            size_t ro = (((size_t)(b * H_ + h)) * L_ + i) * L_ + j;
            s += rel_pos[ro] + rel2d[ro];
            sScore[h][t] = s;
        }
    }
    __syncthreads();

    // --- combine duplicates + 32-wide softmax per head ---
    {
        int h = tid >> 5;          // 0..11
        int t = tid & 31;
        int j = sIdx[t];
        float s = -INFINITY;
        if (sFirst[t]) {
            float bb = 0.f;
#pragma unroll
            for (int t2 = 0; t2 < TOPK_; ++t2)
                if (sIdx[t2] == j) bb += sBbox[h][t2];
            s = sScore[h][t] + bb;
            if (amask[((size_t)b * L_ + i) * L_ + j]) s = NEG_;
        }
        float m = s;
        m = fmaxf(m, __shfl_xor(m, 1));  m = fmaxf(m, __shfl_xor(m, 2));
        m = fmaxf(m, __shfl_xor(m, 4));  m = fmaxf(m, __shfl_xor(m, 8));
        m = fmaxf(m, __shfl_xor(m, 16));
        float e = expf(s - m);            // -inf -> 0
        float sum = e;
        sum += __shfl_xor(sum, 1);  sum += __shfl_xor(sum, 2);
        sum += __shfl_xor(sum, 4);  sum += __shfl_xor(sum, 8);
        sum += __shfl_xor(sum, 16);
        sProb[h][t] = e / sum;
    }
    __syncthreads();

    // --- ctx: out[h, d] = sum_t p[t] * v[j_t, h, d]; lane owns 2 d's ---
    {
        int h = tid >> 5;
        int dd = (tid & 31) * 2;
        float a0 = 0.f, a1 = 0.f;
#pragma unroll
        for (int t = 0; t < TOPK_; ++t) {
            float p = sProb[h][t];
            if (p != 0.f) {
                int j = sIdx[t];
                const float2 v2 = *(const float2*)(qkv + (size_t)(b * L_ + j) * (3 * HID_) + 2 * HID_ + h * D_ + dd);
                a0 = fmaf(p, v2.x, a0);
                a1 = fmaf(p, v2.y, a1);
            }
        }
        float2 o; o.x = a0; o.y = a1;
        *(float2*)(out + (size_t)bi * HID_ + h * D_ + dd) = o;
    }
}

// ---------------------------------------------------------------------------
extern "C" void kernel_launch(void* const* d_in, const int* in_sizes, int n_in,
                              void* d_out, int out_size, void* d_ws, size_t ws_size,
                              hipStream_t stream)
{
    const float* hidden  = (const float*)d_in[0];
    const float* rbe     = (const float*)d_in[1];
    const int*   ridx    = (const int*)d_in[2];
    const unsigned char* amask = (const unsigned char*)d_in[3];
    const float* rel_pos = (const float*)d_in[4];
    const float* rel2d   = (const float*)d_in[5];
    const float* w_qkv   = (const float*)d_in[6];
    const float* q_bias  = (const float*)d_in[7];
    const float* v_bias  = (const float*)d_in[8];
    const float* w_rq    = (const float*)d_in[9];
    const float* b_rq    = (const float*)d_in[10];
    float* out = (float*)d_out;

    const int M = B_ * L_;              // 2048
    float* qkv   = (float*)d_ws;                    // M * 2304
    float* qb    = qkv + (size_t)M * (3 * HID_);    // M * 768
    float* biasq = qb + (size_t)M * HID_;           // 2304

    prep_bias<<<9, 256, 0, stream>>>(q_bias, v_bias, biasq);

    // qkv = hidden @ w_qkv + [q_bias|0|v_bias]
    dim3 g1((3 * HID_) / 128, M / 128);
    gemm_f32<<<g1, 256, 0, stream>>>(hidden, HID_, w_qkv, 3 * HID_, biasq,
                                     qkv, 3 * HID_, M, 3 * HID_, HID_);
    // qb = q @ w_rq + b_rq   (q = qkv cols 0..767, bias already applied)
    dim3 g2(HID_ / 128, M / 128);
    gemm_f32<<<g2, 256, 0, stream>>>(qkv, 3 * HID_, w_rq, HID_, b_rq,
                                     qb, HID_, M, HID_, HID_);

    attn_kernel<<<B_ * L_, 384, 0, stream>>>(qkv, qb, rbe, ridx, amask,
                                             rel_pos, rel2d, out);
}

// Round 6
// 542.176 us; speedup vs baseline: 1.2401x; 1.2401x over previous
//
#include <hip/hip_runtime.h>
#include <hip/hip_bf16.h>
#include <math.h>

#define B_    2
#define L_    1024
#define H_    12
#define D_    64
#define HID_  768
#define TOPK_ 32
#define NEG_  (-100000000.0f)
#define KP_   2304   // tripled K for split-bf16 GEMM

typedef __attribute__((ext_vector_type(8))) short short8;
typedef __attribute__((ext_vector_type(4))) short short4v;
typedef __attribute__((ext_vector_type(4))) float f32x4;

__device__ __forceinline__ void gload16(const void* g, void* l) {
    __builtin_amdgcn_global_load_lds((const __attribute__((address_space(1))) void*)g,
                                     (__attribute__((address_space(3))) void*)l, 16, 0, 0);
}

// ---------------------------------------------------------------------------
// bias vector for the fused qkv GEMM: [q_bias | zeros | v_bias]
// ---------------------------------------------------------------------------
__global__ void prep_bias(const float* __restrict__ qb_,
                          const float* __restrict__ vb_,
                          float* __restrict__ biasq) {
    int n = blockIdx.x * 256 + threadIdx.x;
    if (n >= 3 * HID_) return;
    float v = 0.f;
    if (n < HID_) v = qb_[n];
    else if (n >= 2 * HID_) v = vb_[n - 2 * HID_];
    biasq[n] = v;
}

// ---------------------------------------------------------------------------
// split fp32 A [2048][srcStride] (first 768 cols) -> bf16 [2048][2304] = [hi|hi|lo]
// ---------------------------------------------------------------------------
__global__ __launch_bounds__(256) void split_a(const float* __restrict__ src, int srcStride,
                                               __hip_bfloat16* __restrict__ dst) {
    int idx = blockIdx.x * 256 + threadIdx.x;           // 0 .. 2048*192-1
    int r = idx / 192, c4 = (idx - r * 192) * 4;
    const float4 x = *(const float4*)(src + (size_t)r * srcStride + c4);
    float xs[4] = {x.x, x.y, x.z, x.w};
    short4v h4, l4;
#pragma unroll
    for (int j = 0; j < 4; ++j) {
        __hip_bfloat16 h = __float2bfloat16(xs[j]);
        __hip_bfloat16 l = __float2bfloat16(xs[j] - __bfloat162float(h));
        h4[j] = *(short*)&h;
        l4[j] = *(short*)&l;
    }
    short* d = (short*)(dst + (size_t)r * KP_ + c4);
    *(short4v*)(d)         = h4;
    *(short4v*)(d + 768)   = h4;
    *(short4v*)(d + 1536)  = l4;
}

// ---------------------------------------------------------------------------
// transpose + split weights: src [768][N] f32 -> dst [N][2304] bf16 = [hi|lo|hi]
// ---------------------------------------------------------------------------
__global__ __launch_bounds__(256) void split_w(const float* __restrict__ src, int N,
                                               __hip_bfloat16* __restrict__ dst) {
    __shared__ float tile[32][33];
    const int n0 = blockIdx.x * 32, k0 = blockIdx.y * 32;
    const int tx = threadIdx.x & 31, ty = threadIdx.x >> 5;
#pragma unroll
    for (int p = 0; p < 4; ++p) {
        int r = p * 8 + ty;
        tile[r][tx] = src[(size_t)(k0 + r) * N + n0 + tx];
    }
    __syncthreads();
#pragma unroll
    for (int p = 0; p < 4; ++p) {
        int nl = p * 8 + ty;
        float xv = tile[tx][nl];
        __hip_bfloat16 h = __float2bfloat16(xv);
        __hip_bfloat16 l = __float2bfloat16(xv - __bfloat162float(h));
        size_t base = (size_t)(n0 + nl) * KP_ + k0 + tx;
        dst[base]        = h;
        dst[base + 768]  = l;
        dst[base + 1536] = h;
    }
}

// ---------------------------------------------------------------------------
// split-bf16 MFMA GEMM: C[M][ldc] = A'[M][2304] x Bt'[N][2304] + bias
// ---------------------------------------------------------------------------
template<int BM, int BN>
__global__ __launch_bounds__(256) void gemm_split(
    const __hip_bfloat16* __restrict__ A,
    const __hip_bfloat16* __restrict__ Bt,
    const float* __restrict__ bias,
    float* __restrict__ C, int ldc)
{
    constexpr int NT  = KP_ / 64;
    constexpr int ACH = BM / 32;
    constexpr int BCH = BN / 32;
    constexpr int MI  = BM / 32;
    constexpr int NI  = BN / 32;
    __shared__ __align__(16) char smem[(BM + BN) * 128];

    const int tid  = threadIdx.x;
    const int wid  = tid >> 6, lane = tid & 63;
    const int wr   = wid >> 1, wc = wid & 1;
    const int bm   = blockIdx.y * BM, bn = blockIdx.x * BN;
    const int r4   = lane >> 4, l15 = lane & 15;

    f32x4 acc[MI][NI];
#pragma unroll
    for (int mi = 0; mi < MI; ++mi)
#pragma unroll
        for (int ni = 0; ni < NI; ++ni) acc[mi][ni] = (f32x4){0.f, 0.f, 0.f, 0.f};

    const char* Ab  = (const char*)A;
    const char* Btb = (const char*)Bt;

    for (int kt = 0; kt < NT; ++kt) {
        __syncthreads();
#pragma unroll
        for (int c = 0; c < ACH; ++c) {
            int slot = c * 4096 + tid * 16;
            int R = slot >> 7, cb = (slot >> 4) & 7;
            const char* g = Ab + (size_t)(bm + R) * (KP_ * 2) + kt * 128 + ((cb ^ (R & 7)) << 4);
            gload16(g, smem + c * 4096 + wid * 1024);
        }
#pragma unroll
        for (int c = 0; c < BCH; ++c) {
            int slot = c * 4096 + tid * 16;
            int R = slot >> 7, cb = (slot >> 4) & 7;
            const char* g = Btb + (size_t)(bn + R) * (KP_ * 2) + kt * 128 + ((cb ^ (R & 7)) << 4);
            gload16(g, smem + BM * 128 + c * 4096 + wid * 1024);
        }
        __syncthreads();

#pragma unroll
        for (int kk = 0; kk < 2; ++kk) {
            short8 af[MI], bfv[NI];
#pragma unroll
            for (int mi = 0; mi < MI; ++mi) {
                int m_loc = wr * (BM / 2) + mi * 16 + l15;
                int off = (m_loc * 128 + kk * 64 + r4 * 16) ^ ((m_loc & 7) << 4);
                af[mi] = *(const short8*)(smem + off);
            }
#pragma unroll
            for (int ni = 0; ni < NI; ++ni) {
                int n_loc = wc * (BN / 2) + ni * 16 + l15;
                int off = BM * 128 + ((n_loc * 128 + kk * 64 + r4 * 16) ^ ((n_loc & 7) << 4));
                bfv[ni] = *(const short8*)(smem + off);
            }
#pragma unroll
            for (int mi = 0; mi < MI; ++mi)
#pragma unroll
                for (int ni = 0; ni < NI; ++ni)
                    acc[mi][ni] = __builtin_amdgcn_mfma_f32_16x16x32_bf16(
                        af[mi], bfv[ni], acc[mi][ni], 0, 0, 0);
        }
    }

#pragma unroll
    for (int mi = 0; mi < MI; ++mi) {
        int row = bm + wr * (BM / 2) + mi * 16 + r4 * 4;
#pragma unroll
        for (int ni = 0; ni < NI; ++ni) {
            int col = bn + wc * (BN / 2) + ni * 16 + l15;
            float bv = bias[col];
#pragma unroll
            for (int reg = 0; reg < 4; ++reg)
                C[(size_t)(row + reg) * ldc + col] = acc[mi][ni][reg] + bv;
        }
    }
}

// ---------------------------------------------------------------------------
// Sparse gather-attention. One block per (b,i); 384 threads.
// Thread (h=tid>>5, t=tid&31) owns one (t,h) score pair: no shuffles in the
// score phases, 16 independent float4 loads per dot, V prefetched to regs.
// ---------------------------------------------------------------------------
__global__ __launch_bounds__(384) void attn_kernel(
    const float* __restrict__ qkv,   // [B*L][2304]  q|k|v (biases applied)
    const float* __restrict__ qb,    // [B*L][768]
    const float* __restrict__ rbe,   // [B*L][32][768]
    const int*   __restrict__ ridx,  // [B*L][32]
    const unsigned char* __restrict__ amask, // [B][L][L]
    const float* __restrict__ rel_pos,   // [B][12][L][L]
    const float* __restrict__ rel2d,     // [B][12][L][L]
    float* __restrict__ out)             // [B*L][768]
{
    const int bi = blockIdx.x;
    const int b = bi >> 10, i = bi & (L_ - 1);
    const int tid = threadIdx.x;
    const int h = tid >> 5, t = tid & 31;   // 384 = 12 heads x 32 slots
    const float scale = 0.125f;

    __shared__ __align__(16) float sQ[HID_];
    __shared__ __align__(16) float sQb[HID_];
    __shared__ int   sIdx[TOPK_];
    __shared__ unsigned char sFirst[TOPK_];
    __shared__ unsigned char sMask[TOPK_];
    __shared__ float sRel[H_][TOPK_];
    __shared__ float sBbox[H_][TOPK_];
    __shared__ float sScore[H_][TOPK_];
    __shared__ float sProb[H_][TOPK_];

    // phase 0: q rows (scaled) + indices into LDS
    {
        const float* qrow  = qkv + (size_t)bi * (3 * HID_);
        const float* qbrow = qb + (size_t)bi * HID_;
        for (int d = tid; d < HID_; d += 384) {
            sQ[d]  = qrow[d]  * scale;
            sQb[d] = qbrow[d] * scale;
        }
        if (tid < TOPK_) sIdx[tid] = ridx[bi * TOPK_ + tid];
    }
    __syncthreads();

    const int j = sIdx[t];

    // phase 1: random rel/mask gathers — one per thread, all issued at once
    {
        size_t ro = (((size_t)(b * H_ + h)) * L_ + i) * L_ + j;
        sRel[h][t] = rel_pos[ro] + rel2d[ro];
        if (tid < TOPK_) {
            int jj = sIdx[tid];
            sMask[tid] = amask[((size_t)b * L_ + i) * L_ + jj];
            unsigned char f = 1;
            for (int t2 = 0; t2 < tid; ++t2)
                if (sIdx[t2] == jj) { f = 0; break; }
            sFirst[tid] = f;
        }
    }

    // phase 2: both dot products, one thread per (t,h), no cross-lane ops.
    {
        const float* rrow = rbe + ((size_t)bi * TOPK_ + t) * HID_ + h * D_;
        const float* krow = qkv + (size_t)(b * L_ + j) * (3 * HID_) + HID_ + h * D_;
        const float* qbh  = sQb + h * D_;
        const float* qh   = sQ + h * D_;
        float accB0 = 0.f, accB1 = 0.f, accB2 = 0.f, accB3 = 0.f;
        float accK0 = 0.f, accK1 = 0.f, accK2 = 0.f, accK3 = 0.f;
#pragma unroll
        for (int it = 0; it < 16; it += 4) {
            const float4 r0 = *(const float4*)(rrow + (it + 0) * 4);
            const float4 r1 = *(const float4*)(rrow + (it + 1) * 4);
            const float4 r2 = *(const float4*)(rrow + (it + 2) * 4);
            const float4 r3 = *(const float4*)(rrow + (it + 3) * 4);
            const float4 k0 = *(const float4*)(krow + (it + 0) * 4);
            const float4 k1 = *(const float4*)(krow + (it + 1) * 4);
            const float4 k2 = *(const float4*)(krow + (it + 2) * 4);
            const float4 k3 = *(const float4*)(krow + (it + 3) * 4);
            const float4 qb0 = *(const float4*)(qbh + (it + 0) * 4);
            const float4 qb1 = *(const float4*)(qbh + (it + 1) * 4);
            const float4 qb2 = *(const float4*)(qbh + (it + 2) * 4);
            const float4 qb3 = *(const float4*)(qbh + (it + 3) * 4);
            const float4 q0 = *(const float4*)(qh + (it + 0) * 4);
            const float4 q1 = *(const float4*)(qh + (it + 1) * 4);
            const float4 q2 = *(const float4*)(qh + (it + 2) * 4);
            const float4 q3 = *(const float4*)(qh + (it + 3) * 4);
            accB0 = fmaf(r0.x, qb0.x, fmaf(r0.y, qb0.y, fmaf(r0.z, qb0.z, fmaf(r0.w, qb0.w, accB0))));
            accB1 = fmaf(r1.x, qb1.x, fmaf(r1.y, qb1.y, fmaf(r1.z, qb1.z, fmaf(r1.w, qb1.w, accB1))));
            accB2 = fmaf(r2.x, qb2.x, fmaf(r2.y, qb2.y, fmaf(r2.z, qb2.z, fmaf(r2.w, qb2.w, accB2))));
            accB3 = fmaf(r3.x, qb3.x, fmaf(r3.y, qb3.y, fmaf(r3.z, qb3.z, fmaf(r3.w, qb3.w, accB3))));
            accK0 = fmaf(k0.x, q0.x, fmaf(k0.y, q0.y, fmaf(k0.z, q0.z, fmaf(k0.w, q0.w, accK0))));
            accK1 = fmaf(k1.x, q1.x, fmaf(k1.y, q1.y, fmaf(k1.z, q1.z, fmaf(k1.w, q1.w, accK1))));
            accK2 = fmaf(k2.x, q2.x, fmaf(k2.y, q2.y, fmaf(k2.z, q2.z, fmaf(k2.w, q2.w, accK2))));
            accK3 = fmaf(k3.x, q3.x, fmaf(k3.y, q3.y, fmaf(k3.z, q3.z, fmaf(k3.w, q3.w, accK3))));
        }
        sBbox[h][t]  = (accB0 + accB1) + (accB2 + accB3);
        sScore[h][t] = (accK0 + accK1) + (accK2 + accK3) + sRel[h][t];
    }

    // prefetch V to registers (depends only on sIdx) — latency hides under
    // the barrier + softmax below. Thread covers (head h, dims dd,dd+1).
    const int dd = (t) * 2;
    float2 vpre[TOPK_];
    {
        const float* vbase = qkv + (size_t)b * L_ * (3 * HID_) + 2 * HID_ + h * D_ + dd;
#pragma unroll
        for (int tt = 0; tt < TOPK_; ++tt)
            vpre[tt] = *(const float2*)(vbase + (size_t)sIdx[tt] * (3 * HID_));
    }
    __syncthreads();

    // softmax over the <=32 unique columns per head (reduce over t = lane&31)
    {
        float s = -INFINITY;
        if (sFirst[t]) {
            float bb = 0.f;
#pragma unroll
            for (int t2 = 0; t2 < TOPK_; ++t2)
                if (sIdx[t2] == j) bb += sBbox[h][t2];
            s = sScore[h][t] + bb;
            if (sMask[t]) s = NEG_;
        }
        float m = s;
        m = fmaxf(m, __shfl_xor(m, 1));  m = fmaxf(m, __shfl_xor(m, 2));
        m = fmaxf(m, __shfl_xor(m, 4));  m = fmaxf(m, __shfl_xor(m, 8));
        m = fmaxf(m, __shfl_xor(m, 16));
        float e = expf(s - m);
        float sum = e;
        sum += __shfl_xor(sum, 1);  sum += __shfl_xor(sum, 2);
        sum += __shfl_xor(sum, 4);  sum += __shfl_xor(sum, 8);
        sum += __shfl_xor(sum, 16);
        sProb[h][t] = e / sum;
    }
    __syncthreads();

    // ctx from prefetched V: out[h, dd..dd+1] = sum_t p[t] * v[j_t]
    {
        float a0 = 0.f, a1 = 0.f;
#pragma unroll
        for (int tt = 0; tt < TOPK_; ++tt) {
            float p = sProb[h][tt];
            a0 = fmaf(p, vpre[tt].x, a0);
            a1 = fmaf(p, vpre[tt].y, a1);
        }
        float2 o; o.x = a0; o.y = a1;
        *(float2*)(out + (size_t)bi * HID_ + h * D_ + dd) = o;
    }
}

// ---------------------------------------------------------------------------
extern "C" void kernel_launch(void* const* d_in, const int* in_sizes, int n_in,
                              void* d_out, int out_size, void* d_ws, size_t ws_size,
                              hipStream_t stream)
{
    const float* hidden  = (const float*)d_in[0];
    const float* rbe     = (const float*)d_in[1];
    const int*   ridx    = (const int*)d_in[2];
    const unsigned char* amask = (const unsigned char*)d_in[3];
    const float* rel_pos = (const float*)d_in[4];
    const float* rel2d   = (const float*)d_in[5];
    const float* w_qkv   = (const float*)d_in[6];
    const float* q_bias  = (const float*)d_in[7];
    const float* v_bias  = (const float*)d_in[8];
    const float* w_rq    = (const float*)d_in[9];
    const float* b_rq    = (const float*)d_in[10];
    float* out = (float*)d_out;

    const int M = B_ * L_;   // 2048
    char* ws = (char*)d_ws;
    float* qkv   = (float*)(ws);                                  // 18.87 MB
    float* qb    = (float*)(ws + 18874368);                       //  6.29 MB
    float* biasq = (float*)(ws + 25165824);                       //  9.2 KB
    __hip_bfloat16* A1  = (__hip_bfloat16*)(ws + 25175040);       //  9.44 MB
    __hip_bfloat16* A2  = (__hip_bfloat16*)(ws + 34612224);       //  9.44 MB
    __hip_bfloat16* Bt1 = (__hip_bfloat16*)(ws + 44049408);       // 10.62 MB
    __hip_bfloat16* Bt2 = (__hip_bfloat16*)(ws + 54666240);       //  3.54 MB

    prep_bias<<<9, 256, 0, stream>>>(q_bias, v_bias, biasq);
    split_a<<<1536, 256, 0, stream>>>(hidden, HID_, A1);
    split_w<<<dim3(2304 / 32, 768 / 32), 256, 0, stream>>>(w_qkv, 3 * HID_, Bt1);
    split_w<<<dim3(768 / 32, 768 / 32), 256, 0, stream>>>(w_rq, HID_, Bt2);

    // qkv = hidden @ w_qkv + [q_bias|0|v_bias]   (BM=128, BN=64: 576 blocks)
    gemm_split<128, 64><<<dim3((3 * HID_) / 64, M / 128), 256, 0, stream>>>(
        A1, Bt1, biasq, qkv, 3 * HID_);

    split_a<<<1536, 256, 0, stream>>>(qkv, 3 * HID_, A2);

    // qb = q @ w_rq + b_rq   (BM=64, BN=64: 384 blocks)
    gemm_split<64, 64><<<dim3(HID_ / 64, M / 64), 256, 0, stream>>>(
        A2, Bt2, b_rq, qb, HID_);

    attn_kernel<<<B_ * L_, 384, 0, stream>>>(qkv, qb, rbe, ridx, amask,
                                             rel_pos, rel2d, out);
}